// Round 8
// baseline (285.975 us; speedup 1.0000x reference)
//
#include <hip/hip_runtime.h>

#define NUM_USERS 100000
#define NUM_ITEMS 200000
#define NNODES    300000   // NUM_USERS + NUM_ITEMS
#define EDIM      64
#define NEDGES    1200000
#define BATCH     4096
#define CHUNK     1024
#define NCHUNKS   ((NNODES + CHUNK - 1) / CHUNK)   // 293

static inline size_t align256(size_t x) { return (x + 255) & ~(size_t)255; }

__device__ __forceinline__ void f4add(float4& a, const float4& b) {
    a.x += b.x; a.y += b.y; a.z += b.z; a.w += b.w;
}

// ---------------- marking + CSR build (2 fused edge passes) ----------------

__global__ void mark_sampled_k(const int* __restrict__ users, const int* __restrict__ items,
                               unsigned char* __restrict__ mS) {
    int t = (int)(blockIdx.x * blockDim.x + threadIdx.x);
    if (t >= 2 * BATCH) return;
    int node = (t < BATCH) ? users[t] : (NUM_USERS + items[t - BATCH]);
    mS[node] = 1;
}

// Pass 1 over edges: histogram counts[dst] + markA (mA[src]=1 if dst sampled).
__global__ void histA_k(const int* __restrict__ src, const int* __restrict__ dst,
                        int* __restrict__ counts, const unsigned char* __restrict__ mS,
                        unsigned char* __restrict__ mA) {
    int e = (int)(blockIdx.x * blockDim.x + threadIdx.x);
    if (e >= NEDGES) return;
    int d = dst[e];
    atomicAdd(&counts[d], 1);
    if (mS[d]) mA[src[e]] = 1;
}

__global__ void scan_chunk_k(const int* __restrict__ counts, int* __restrict__ row_ptr,
                             int* __restrict__ chunk_tot) {
    __shared__ int sm[256];
    int t = threadIdx.x;
    int base = (int)blockIdx.x * CHUNK + t * 4;
    int v0 = (base + 0 < NNODES) ? counts[base + 0] : 0;
    int v1 = (base + 1 < NNODES) ? counts[base + 1] : 0;
    int v2 = (base + 2 < NNODES) ? counts[base + 2] : 0;
    int v3 = (base + 3 < NNODES) ? counts[base + 3] : 0;
    int ts = v0 + v1 + v2 + v3;
    sm[t] = ts;
    __syncthreads();
    for (int off = 1; off < 256; off <<= 1) {
        int x = (t >= off) ? sm[t - off] : 0;
        __syncthreads();
        sm[t] += x;
        __syncthreads();
    }
    int run = sm[t] - ts;
    if (t == 255) chunk_tot[blockIdx.x] = sm[255];
    if (base + 0 < NNODES) row_ptr[base + 0] = run; run += v0;
    if (base + 1 < NNODES) row_ptr[base + 1] = run; run += v1;
    if (base + 2 < NNODES) row_ptr[base + 2] = run; run += v2;
    if (base + 3 < NNODES) row_ptr[base + 3] = run;
}

// 64-lane shfl scan of the 293 chunk totals (exclusive, in-place).
__global__ void scan_tops_k(int* __restrict__ chunk_tot, int* __restrict__ row_ptr) {
    int lane = threadIdx.x & 63;
    int carry = 0;
    for (int base = 0; base < NCHUNKS; base += 64) {
        int idx = base + lane;
        int v = (idx < NCHUNKS) ? chunk_tot[idx] : 0;
        int x = v;
        #pragma unroll
        for (int off = 1; off < 64; off <<= 1) {
            int t = __shfl_up(x, off, 64);
            if (lane >= off) x += t;
        }
        if (idx < NCHUNKS) chunk_tot[idx] = carry + x - v;   // exclusive
        carry += __shfl(x, 63, 64);
    }
    if (lane == 0) row_ptr[NNODES] = carry;
}

__global__ void add_off_k(int* __restrict__ row_ptr, const int* __restrict__ chunk_tot) {
    int i = (int)(blockIdx.x * blockDim.x + threadIdx.x);
    if (i < NNODES) row_ptr[i] += chunk_tot[i / CHUNK];
}

// Pass 2 over edges: CSR fill + markB (mB[src]=1 if dst in mS|mA).
__global__ void fillB_k(const int* __restrict__ src, const int* __restrict__ dst,
                        const int* __restrict__ row_ptr, int* __restrict__ cursor,
                        int* __restrict__ ssrc, const unsigned char* __restrict__ mS,
                        const unsigned char* __restrict__ mA, unsigned char* __restrict__ mB) {
    int e = (int)(blockIdx.x * blockDim.x + threadIdx.x);
    if (e >= NEDGES) return;
    int d = dst[e];
    int s = src[e];
    int pos = atomicAdd(&cursor[d], 1);
    ssrc[row_ptr[d] + pos] = s;
    if (mS[d] | mA[d]) mB[s] = 1;
}

// Compact active sets into worklists (order nondeterministic; per-node output
// is order-independent => bitwise deterministic results).
__global__ void build_wl_k(const unsigned char* __restrict__ mS, const unsigned char* __restrict__ mA,
                           const unsigned char* __restrict__ mB, int* __restrict__ wl1,
                           int* __restrict__ wl2, int* __restrict__ wl_n) {
    int i = (int)(blockIdx.x * blockDim.x + threadIdx.x);
    if (i >= NNODES) return;
    unsigned char s = mS[i], a = mA[i], b = mB[i];
    if (s | a | b) wl1[atomicAdd(&wl_n[0], 1)] = i;
    if (s | a)     wl2[atomicAdd(&wl_n[1], 1)] = i;
}

// ---------------- propagation: worklist grid-stride, float4 x 4 edge slots ----------------

#define PROP_BLOCKS 2048   // 8192 waves

__global__ __launch_bounds__(256) void prop_f4_k(
        const float* __restrict__ cur, float* __restrict__ nxt,
        const int* __restrict__ row_ptr, const int* __restrict__ ssrc,
        const int* __restrict__ wl, const int* __restrict__ wl_n) {
    int lane = threadIdx.x & 63;
    int sub = lane >> 4, d16 = lane & 15;
    int gw = (int)((blockIdx.x * blockDim.x + threadIdx.x) >> 6);
    int nw = (int)((gridDim.x * blockDim.x) >> 6);
    int n = wl_n[0];
    const float4* cur4 = (const float4*)cur;
    for (int i = gw; i < n; i += nw) {
        int node = wl[i];
        int s0 = row_ptr[node], s1 = row_ptr[node + 1];
        float4 acc0 = {0.f, 0.f, 0.f, 0.f}, acc1 = {0.f, 0.f, 0.f, 0.f};
        int e = s0;
        for (; e + 8 <= s1; e += 8) {
            int i0 = ssrc[e + sub];
            int i1 = ssrc[e + 4 + sub];
            float4 v0 = cur4[(size_t)i0 * 16 + d16];
            float4 v1 = cur4[(size_t)i1 * 16 + d16];
            f4add(acc0, v0);
            f4add(acc1, v1);
        }
        int ee0 = e + sub;
        if (ee0 < s1) f4add(acc0, cur4[(size_t)ssrc[ee0] * 16 + d16]);
        int ee1 = e + 4 + sub;
        if (ee1 < s1) f4add(acc1, cur4[(size_t)ssrc[ee1] * 16 + d16]);
        f4add(acc0, acc1);
        acc0.x += __shfl_xor(acc0.x, 16, 64); acc0.x += __shfl_xor(acc0.x, 32, 64);
        acc0.y += __shfl_xor(acc0.y, 16, 64); acc0.y += __shfl_xor(acc0.y, 32, 64);
        acc0.z += __shfl_xor(acc0.z, 16, 64); acc0.z += __shfl_xor(acc0.z, 32, 64);
        acc0.w += __shfl_xor(acc0.w, 16, 64); acc0.w += __shfl_xor(acc0.w, 32, 64);
        if (sub == 0) ((float4*)nxt)[(size_t)node * 16 + d16] = acc0;
    }
}

// Fused: accs[w] = emb+bufA+bufB at sampled node + layer-3 gather of bufB.
__global__ __launch_bounds__(256) void final_acc_k(
        const float* __restrict__ emb, const float* __restrict__ bufA,
        const float* __restrict__ bufB, const int* __restrict__ users,
        const int* __restrict__ items, const int* __restrict__ row_ptr,
        const int* __restrict__ ssrc, float* __restrict__ accs) {
    int t = (int)(blockIdx.x * blockDim.x + threadIdx.x);
    int w = t >> 6;
    int lane = threadIdx.x & 63, sub = lane >> 4, d16 = lane & 15;
    if (w >= 2 * BATCH) return;
    int node = (w < BATCH) ? users[w] : (NUM_USERS + items[w - BATCH]);
    int s0 = row_ptr[node], s1 = row_ptr[node + 1];
    const float4* b4 = (const float4*)bufB;
    float4 acc0 = {0.f, 0.f, 0.f, 0.f}, acc1 = {0.f, 0.f, 0.f, 0.f};
    int e = s0;
    for (; e + 8 <= s1; e += 8) {
        int i0 = ssrc[e + sub];
        int i1 = ssrc[e + 4 + sub];
        f4add(acc0, b4[(size_t)i0 * 16 + d16]);
        f4add(acc1, b4[(size_t)i1 * 16 + d16]);
    }
    int ee0 = e + sub;
    if (ee0 < s1) f4add(acc0, b4[(size_t)ssrc[ee0] * 16 + d16]);
    int ee1 = e + 4 + sub;
    if (ee1 < s1) f4add(acc1, b4[(size_t)ssrc[ee1] * 16 + d16]);
    f4add(acc0, acc1);
    acc0.x += __shfl_xor(acc0.x, 16, 64); acc0.x += __shfl_xor(acc0.x, 32, 64);
    acc0.y += __shfl_xor(acc0.y, 16, 64); acc0.y += __shfl_xor(acc0.y, 32, 64);
    acc0.z += __shfl_xor(acc0.z, 16, 64); acc0.z += __shfl_xor(acc0.z, 32, 64);
    acc0.w += __shfl_xor(acc0.w, 16, 64); acc0.w += __shfl_xor(acc0.w, 32, 64);
    if (sub == 0) {
        size_t ro = (size_t)node * 16 + d16;
        float4 ev = ((const float4*)emb)[ro];
        float4 av = ((const float4*)bufA)[ro];
        float4 bv = ((const float4*)bufB)[ro];
        float4 r;
        r.x = ev.x + av.x + bv.x + acc0.x;
        r.y = ev.y + av.y + bv.y + acc0.y;
        r.z = ev.z + av.z + bv.z + acc0.z;
        r.w = ev.w + av.w + bv.w + acc0.w;
        ((float4*)accs)[(size_t)w * 16 + d16] = r;
    }
}

__global__ void dot_out_k(const float* __restrict__ accs, float* __restrict__ out) {
    int t = (int)(blockIdx.x * blockDim.x + threadIdx.x);
    int b = t >> 6, lane = t & 63;
    if (b >= BATCH) return;
    float p = accs[(size_t)b * EDIM + lane] * accs[(size_t)(BATCH + b) * EDIM + lane];
    #pragma unroll
    for (int off = 32; off; off >>= 1) p += __shfl_down(p, off, 64);
    if (lane == 0) out[b] = p * (1.0f / 16.0f);
}

// ---------------- fallback (baseline atomic path) ----------------

__global__ void acc_batch_k(const float* __restrict__ cur, const int* __restrict__ users,
                            const int* __restrict__ items, float* __restrict__ accs, int first) {
    int t = (int)(blockIdx.x * blockDim.x + threadIdx.x);
    int row = t >> 6, lane = t & 63;
    if (row >= 2 * BATCH) return;
    int node = (row < BATCH) ? users[row] : (NUM_USERS + items[row - BATCH]);
    float v = cur[(size_t)node * EDIM + lane];
    size_t o = (size_t)row * EDIM + lane;
    if (first) accs[o] = v;
    else       accs[o] += v;
}

__global__ void scatter_add_k(const float* __restrict__ cur, float* __restrict__ nxt,
                              const int* __restrict__ src, const int* __restrict__ dst) {
    int w = (int)((blockIdx.x * blockDim.x + threadIdx.x) >> 6);
    int lane = threadIdx.x & 63;
    if (w >= NEDGES) return;
    float v = cur[(size_t)src[w] * EDIM + lane];
    atomicAdd(&nxt[(size_t)dst[w] * EDIM + lane], v);
}

extern "C" void kernel_launch(void* const* d_in, const int* in_sizes, int n_in,
                              void* d_out, int out_size, void* d_ws, size_t ws_size,
                              hipStream_t stream) {
    const float* emb   = (const float*)d_in[0];
    const int*   edge  = (const int*)d_in[1];
    const int*   src   = edge;            // edge_index[0]
    const int*   dst   = edge + NEDGES;   // edge_index[1]
    const int*   users = (const int*)d_in[2];
    const int*   items = (const int*)d_in[3];
    float*       out   = (float*)d_out;

    const size_t bufBytes = (size_t)NNODES * EDIM * sizeof(float); // 76.8 MB

    // workspace layout (zero-region is contiguous: one memset)
    size_t off = 0;
    float* bufA = (float*)((char*)d_ws + off); off = align256(off + bufBytes);
    float* bufB = (float*)((char*)d_ws + off); off = align256(off + bufBytes);
    float* accs = (float*)((char*)d_ws + off); off = align256(off + (size_t)2 * BATCH * EDIM * sizeof(float));
    int* row_ptr = (int*)((char*)d_ws + off); off = align256(off + (size_t)(NNODES + 1) * sizeof(int));
    int* ssrc    = (int*)((char*)d_ws + off); off = align256(off + (size_t)NEDGES * sizeof(int));
    int* wl1     = (int*)((char*)d_ws + off); off = align256(off + (size_t)NNODES * sizeof(int));
    int* wl2     = (int*)((char*)d_ws + off); off = align256(off + (size_t)NNODES * sizeof(int));
    const size_t zeroBase = off;
    int* counts    = (int*)((char*)d_ws + off); off += (size_t)NNODES * sizeof(int);
    int* cursor    = (int*)((char*)d_ws + off); off += (size_t)NNODES * sizeof(int);
    int* chunk_tot = (int*)((char*)d_ws + off); off += (size_t)NCHUNKS * sizeof(int);
    int* wl_n      = (int*)((char*)d_ws + off); off += 2 * sizeof(int);
    unsigned char* mS = (unsigned char*)((char*)d_ws + off); off += (size_t)NNODES;
    unsigned char* mA = (unsigned char*)((char*)d_ws + off); off += (size_t)NNODES;
    unsigned char* mB = (unsigned char*)((char*)d_ws + off); off += (size_t)NNODES;
    const size_t zeroBytes = off - zeroBase;
    const size_t needed = align256(off);

    const dim3 blk(256);
    const int edgeBlocks = (NEDGES + 255) / 256;
    const int nodeBlocks = (NNODES + 255) / 256;
    const int sampBlocks = (2 * BATCH * 64 + 255) / 256;
    const int dotBlocks  = (BATCH * 64 + 255) / 256;

    if (ws_size >= needed) {
        hipMemsetAsync((char*)d_ws + zeroBase, 0, zeroBytes, stream);
        mark_sampled_k<<<(2 * BATCH + 255) / 256, blk, 0, stream>>>(users, items, mS);
        histA_k<<<edgeBlocks, blk, 0, stream>>>(src, dst, counts, mS, mA);
        scan_chunk_k<<<NCHUNKS, blk, 0, stream>>>(counts, row_ptr, chunk_tot);
        scan_tops_k<<<1, 64, 0, stream>>>(chunk_tot, row_ptr);
        add_off_k<<<nodeBlocks, blk, 0, stream>>>(row_ptr, chunk_tot);
        fillB_k<<<edgeBlocks, blk, 0, stream>>>(src, dst, row_ptr, cursor, ssrc, mS, mA, mB);
        build_wl_k<<<nodeBlocks, blk, 0, stream>>>(mS, mA, mB, wl1, wl2, wl_n);

        prop_f4_k<<<PROP_BLOCKS, blk, 0, stream>>>(emb,  bufA, row_ptr, ssrc, wl1, wl_n);      // layer 1
        prop_f4_k<<<PROP_BLOCKS, blk, 0, stream>>>(bufA, bufB, row_ptr, ssrc, wl2, wl_n + 1);  // layer 2
        final_acc_k<<<sampBlocks, blk, 0, stream>>>(emb, bufA, bufB, users, items, row_ptr, ssrc, accs);
        dot_out_k<<<dotBlocks, blk, 0, stream>>>(accs, out);
    } else {
        // ---- fallback: baseline atomic path ----
        const int scatterBlocks = (NEDGES + 3) / 4;
        acc_batch_k<<<sampBlocks, blk, 0, stream>>>(emb, users, items, accs, 1);
        const float* cur = emb;
        float* bufs[2] = {bufA, bufB};
        for (int l = 0; l < 3; ++l) {
            float* nxt = bufs[l & 1];
            hipMemsetAsync(nxt, 0, bufBytes, stream);
            scatter_add_k<<<scatterBlocks, blk, 0, stream>>>(cur, nxt, src, dst);
            acc_batch_k<<<sampBlocks, blk, 0, stream>>>(nxt, users, items, accs, 0);
            cur = nxt;
        }
        dot_out_k<<<dotBlocks, blk, 0, stream>>>(accs, out);
    }
}